// Round 1
// baseline (242.483 us; speedup 1.0000x reference)
//
#include <hip/hip_runtime.h>

// Problem constants from setup_inputs(): predicted (S,B,H,W) f32, target (B,S,H,W) f32.
#define SS 10
#define BB 8
#define HH 512
#define WW 512

__global__ __launch_bounds__(256) void shiftpred_kernel(
    const float* __restrict__ pred,   // (S,B,H,W)
    const float* __restrict__ targ,   // (B,S,H,W)
    float* __restrict__ out)          // (S,B,H,W)
{
    // Each thread handles 4 consecutive w. W/4 = 128 quads per row.
    const int W4 = WW / 4;                       // 128
    int tid = blockIdx.x * blockDim.x + threadIdx.x;

    int wq = tid & (W4 - 1);                     // quad index in row
    int h  = (tid >> 7) & (HH - 1);              // 7 bits for 128 quads
    int sb = tid >> 16;                          // 7 + 9 bits consumed
    if (sb >= SS * BB) return;

    int s = sb >> 3;                             // sb / 8
    int b = sb & 7;                              // sb % 8
    int wb = wq << 2;

    const float* pplane = pred + (size_t)sb * (HH * WW);
    const float* tplane = targ + (size_t)(b * SS + s) * (HH * WW);

    // target float4
    float4 t4 = *reinterpret_cast<const float4*>(tplane + h * WW + wb);
    float tv[4] = {t4.x, t4.y, t4.z, t4.w};

    // Stage 3 rows x 6 floats (w-1 .. w+4) of pred in registers.
    float v[3][6];
    bool rowvalid[3];
    #pragma unroll
    for (int xi = 0; xi < 3; ++xi) {
        int hh = h + xi - 1;
        bool rv = (hh >= 0) && (hh < HH);
        rowvalid[xi] = rv;
        int hc = rv ? hh : h;                    // clamp row to stay in-buffer
        const float* rp = pplane + hc * WW + wb;
        float4 c4 = *reinterpret_cast<const float4*>(rp);
        float lft = (wb > 0)        ? rp[-1] : rp[0];   // clamped; masked by validity
        float rgt = (wb + 4 < WW)   ? rp[4]  : rp[3];
        v[xi][0] = lft;  v[xi][1] = c4.x; v[xi][2] = c4.y;
        v[xi][3] = c4.z; v[xi][4] = c4.w; v[xi][5] = rgt;
    }

    float res[4];
    #pragma unroll
    for (int j = 0; j < 4; ++j) {
        int w = wb + j;
        // Shift index 0: (0,0) — always valid. Initializes best.
        float bestc = v[1][j + 1];
        float bestl = fabsf(tv[j] - bestc);
        // Shift indices 1..9: (x,y) for x in -1..1, y in -1..1 (includes the
        // duplicate (0,0); strict < keeps the earlier index, matching argmin).
        #pragma unroll
        for (int xi = 0; xi < 3; ++xi) {
            #pragma unroll
            for (int yi = 0; yi < 3; ++yi) {
                float c = v[xi][j + yi];
                float l = fabsf(tv[j] - c);
                bool valid = rowvalid[xi] && ((unsigned)(w + yi - 1) < (unsigned)WW);
                if (valid && l < bestl) { bestl = l; bestc = c; }
            }
        }
        res[j] = bestc;
    }

    float4 o4 = make_float4(res[0], res[1], res[2], res[3]);
    *reinterpret_cast<float4*>(out + (size_t)sb * (HH * WW) + h * WW + wb) = o4;
}

extern "C" void kernel_launch(void* const* d_in, const int* in_sizes, int n_in,
                              void* d_out, int out_size, void* d_ws, size_t ws_size,
                              hipStream_t stream) {
    const float* pred = (const float*)d_in[0];
    const float* targ = (const float*)d_in[1];
    // d_in[2] (mask) is unused: reference sets weights = ones_like(target).
    float* out = (float*)d_out;

    const int total_threads = SS * BB * HH * (WW / 4);   // 5,242,880
    const int block = 256;
    const int grid = (total_threads + block - 1) / block; // 20,480
    shiftpred_kernel<<<grid, block, 0, stream>>>(pred, targ, out);
}